// Round 7
// baseline (406.287 us; speedup 1.0000x reference)
//
#include <hip/hip_runtime.h>

#define NUM_FACES 400000
#define NVIEW 4
#define NCHAN 64
#define IMGS 512
#define XTILES (IMGS / 64)
#define NBUCKET 1024   // 32x32 buckets of 16x16 px

typedef float f32x4 __attribute__((ext_vector_type(4)));
typedef float f32x2 __attribute__((ext_vector_type(2)));

__device__ __forceinline__ unsigned short f2bf(float f) {
    unsigned int u = __float_as_uint(f);
    return (unsigned short)((u + 0x7FFFu + ((u >> 16) & 1u)) >> 16);  // RNE
}

__device__ __forceinline__ void project_view(
    const float* __restrict__ cam_rot, const float* __restrict__ cam_trans,
    const float* __restrict__ Kmat, int v, float px, float py, float pz,
    float& x, float& y)
{
    const float* R  = cam_rot   + v * 9;
    const float* t  = cam_trans + v * 3;
    const float* Km = Kmat      + v * 9;
    float cx = R[0] * px + R[1] * py + R[2] * pz + t[0];
    float cy = R[3] * px + R[4] * py + R[5] * pz + t[1];
    float cz = R[6] * px + R[7] * py + R[8] * pz + t[2];
    float qx = Km[0] * cx + Km[1] * cy + Km[2] * cz;
    float qy = Km[3] * cx + Km[4] * cy + Km[5] * cz;
    float qz = Km[6] * cx + Km[7] * cy + Km[8] * cz;
    x = qx / qz;
    y = qy / qz;
}

// ---------------------------------------------------------------------------
// Kernel 0 (fused): [0,total_pix) scatters pix_to_face into the visibility
// table; [total_pix, total_pix+N*V) projects vertex x view, marks touched
// (v,y,x-tile) flags, and (for v==0) builds the spatial-sort histogram +
// per-vertex bucket id. Racy same-value byte stores are fine.
// ---------------------------------------------------------------------------
__global__ void prep_kernel(const int* __restrict__ p2f,
                            unsigned char* __restrict__ table,   // [V,NUM_FACES]
                            const float* __restrict__ verts,
                            const float* __restrict__ cam_rot,
                            const float* __restrict__ cam_trans,
                            const float* __restrict__ Kmat,
                            unsigned char* __restrict__ flags,   // [V,S,XTILES]
                            int* __restrict__ hist,              // [NBUCKET]
                            int* __restrict__ tileid,            // [N]
                            int n_verts) {
    const int total_pix = NVIEW * IMGS * IMGS;
    int i = blockIdx.x * blockDim.x + threadIdx.x;
    if (i < total_pix) {
        int v = i / (IMGS * IMGS);
        int f = p2f[i];
        if (f >= 0) table[(size_t)v * NUM_FACES + f] = 1;
        return;
    }
    int j = i - total_pix;
    int n = j >> 2;
    int v = j & 3;
    if (n >= n_verts) return;
    float px = verts[n * 3 + 0], py = verts[n * 3 + 1], pz = verts[n * 3 + 2];
    float x, y;
    project_view(cam_rot, cam_trans, Kmat, v, px, py, pz, x, y);
    int x0 = (int)floorf(x), y0 = (int)floorf(y);
    int cx0 = min(max(x0, 0), IMGS - 1);
    int cx1 = min(max(x0 + 1, 0), IMGS - 1);
    int cy0 = min(max(y0, 0), IMGS - 1);
    int cy1 = min(max(y0 + 1, 0), IMGS - 1);
    unsigned char* fv = flags + (size_t)v * IMGS * XTILES;
    int t00 = cy0 * XTILES + (cx0 >> 6);
    int t10 = cy0 * XTILES + (cx1 >> 6);
    int t01 = cy1 * XTILES + (cx0 >> 6);
    int t11 = cy1 * XTILES + (cx1 >> 6);
    fv[t00] = 1;
    if (t10 != t00) fv[t10] = 1;
    fv[t01] = 1;
    if (t11 != t01) fv[t11] = 1;
    if (v == 0) {
        int bx16 = cx0 >> 4, by16 = cy0 >> 4;    // 16px bucket grid (view 0)
        int b = by16 * 32 + bx16;
        tileid[n] = b;
        atomicAdd(&hist[b], 1);
    }
}

// ---------------------------------------------------------------------------
// Kernel 0c: exclusive prefix scan of the 1024-bucket histogram (one block).
// ---------------------------------------------------------------------------
__global__ __launch_bounds__(1024) void scan_kernel(const int* __restrict__ hist,
                                                    int* __restrict__ offs) {
    __shared__ int lds[NBUCKET];
    int t = threadIdx.x;
    int h = hist[t];
    lds[t] = h;
    __syncthreads();
    for (int d = 1; d < NBUCKET; d <<= 1) {
        int val = (t >= d) ? lds[t - d] : 0;
        __syncthreads();
        lds[t] += val;
        __syncthreads();
    }
    offs[t] = lds[t] - h;  // exclusive
}

// ---------------------------------------------------------------------------
// Kernel 0d: scatter vertex ids into bucket-sorted permutation. Order within
// a bucket is nondeterministic but per-vertex OUTPUT VALUES are not.
// ---------------------------------------------------------------------------
__global__ void scatter_perm_kernel(const int* __restrict__ tileid,
                                    int* __restrict__ offs,
                                    int* __restrict__ perm,
                                    int n_verts) {
    int n = blockIdx.x * blockDim.x + threadIdx.x;
    if (n >= n_verts) return;
    int pos = atomicAdd(&offs[tileid[n]], 1);
    perm[pos] = n;
}

// ---------------------------------------------------------------------------
// Kernel 1: transpose feature [V,C,S,S] f32 -> [V,S,S,C] bf16, skipping
// untouched tiles. f32 reads nontemporal (read-once stream).
// ---------------------------------------------------------------------------
__global__ __launch_bounds__(256) void transpose_feat_kernel(
    const float* __restrict__ feature,
    unsigned short* __restrict__ feat_t,
    const unsigned char* __restrict__ flags)
{
    int b = blockIdx.x;
    int xt = b % XTILES;
    int y  = (b / XTILES) % IMGS;
    int v  = b / (XTILES * IMGS);
    if (!flags[((size_t)v * IMGS + y) * XTILES + xt]) return;

    __shared__ float tile[64 * 65];
    int x0 = xt * 64;
    const size_t SS = (size_t)IMGS * IMGS;

    const float* src = feature + (size_t)v * NCHAN * SS + (size_t)y * IMGS + x0;
#pragma unroll
    for (int i = 0; i < 4; ++i) {
        int lin = i * 256 + threadIdx.x;
        int c  = lin >> 4;
        int xq = (lin & 15) * 4;
        f32x4 val = __builtin_nontemporal_load(
            reinterpret_cast<const f32x4*>(src + (size_t)c * SS + xq));
        tile[c * 65 + xq + 0] = val.x;
        tile[c * 65 + xq + 1] = val.y;
        tile[c * 65 + xq + 2] = val.z;
        tile[c * 65 + xq + 3] = val.w;
    }
    __syncthreads();

    unsigned short* dst = feat_t + (((size_t)v * IMGS + y) * IMGS + x0) * NCHAN;
#pragma unroll
    for (int i = 0; i < 4; ++i) {
        int lin = i * 256 + threadIdx.x;
        int x  = lin >> 4;
        int c0 = (lin & 15) * 4;
        ushort4 w;
        w.x = f2bf(tile[(c0 + 0) * 65 + x]);
        w.y = f2bf(tile[(c0 + 1) * 65 + x]);
        w.z = f2bf(tile[(c0 + 2) * 65 + x]);
        w.w = f2bf(tile[(c0 + 3) * 65 + x]);
        *reinterpret_cast<ushort4*>(dst + (size_t)x * NCHAN + c0) = w;
    }
}

// ---------------------------------------------------------------------------
// Kernel 2: bucket-sorted sampler. One wave = one vertex. Per view, ONE
// 256 B row-pair load per row (lanes 0-31 = column bx, lanes 32-63 = bx+1,
// 2 channels per lane) -> 2 loads/view instead of 4. Column halves combined
// at the end with shfl_xor(32). Blocks are XCD-chunk swizzled so consecutive
// buckets stay on one XCD's L2.
// ---------------------------------------------------------------------------
__global__ __launch_bounds__(256) void project_sample_sorted_kernel(
    const float* __restrict__ verts,
    const int* __restrict__ faces,
    const float* __restrict__ cam_rot,
    const float* __restrict__ cam_trans,
    const float* __restrict__ Kmat,
    const unsigned short* __restrict__ feat_t,   // [V,S,S,C] bf16
    const unsigned char* __restrict__ table,     // [V,NUM_FACES]
    const int* __restrict__ perm,                // [N] bucket-sorted vertex ids
    float* __restrict__ out,                     // [N,C]
    int n_verts)
{
    // bijective XCD chunk swizzle (gridDim.x is a multiple of 8)
    int q = gridDim.x >> 3;
    int logical = (blockIdx.x & 7) * q + (blockIdx.x >> 3);
    int slot = logical * 4 + (threadIdx.x >> 6);
    if (slot >= n_verts) return;
    int n = perm[slot];

    int lane  = threadIdx.x & 63;
    int lhalf = lane >> 5;     // 0: column bx, 1: column bx+1
    int cp    = lane & 31;     // channel pair

    float px = verts[n * 3 + 0];
    float py = verts[n * 3 + 1];
    float pz = verts[n * 3 + 2];
    int f = faces[n];

    float xs[NVIEW], ys[NVIEW], mask[NVIEW];
    float vsum = 0.f;
#pragma unroll
    for (int v = 0; v < NVIEW; ++v) {
        project_view(cam_rot, cam_trans, Kmat, v, px, py, pz, xs[v], ys[v]);
        float m = (f >= 0 && table[(size_t)v * NUM_FACES + f]) ? 1.f : 0.f;
        mask[v] = m;
        vsum += m;
    }
    float wsum = vsum;
    if (vsum == 0.f) {
#pragma unroll
        for (int v = 0; v < NVIEW; ++v) mask[v] = 1.f;
        wsum = (float)NVIEW;
    }

    float accx = 0.f, accy = 0.f;
#pragma unroll
    for (int v = 0; v < NVIEW; ++v) {
        if (mask[v] == 0.f) continue;  // wave-uniform skip
        float x = xs[v], y = ys[v];
        float x0f = floorf(x), y0f = floorf(y);
        float wx1 = x - x0f, wx0 = 1.f - wx1;
        float wy1 = y - y0f, wy0 = 1.f - wy1;
        int ix0 = (int)x0f, iy0 = (int)y0f;
        int ix1 = ix0 + 1, iy1 = iy0 + 1;

        int bx = min(max(ix0, 0), IMGS - 2);
        int k  = bx + lhalf;   // this lane's column
        float wxk = 0.f;
        if (k == ix0 && ix0 >= 0 && ix0 <= IMGS - 1) wxk += wx0;
        if (k == ix1 && ix1 >= 0 && ix1 <= IMGS - 1) wxk += wx1;

        int ry0 = min(max(iy0, 0), IMGS - 1);
        int ry1 = min(max(iy1, 0), IMGS - 1);
        float wyr0 = (iy0 >= 0 && iy0 <= IMGS - 1) ? wy0 : 0.f;
        float wyr1 = (iy1 >= 0 && iy1 <= IMGS - 1) ? wy1 : 0.f;

        const unsigned int* fv32 = reinterpret_cast<const unsigned int*>(
            feat_t + (size_t)v * IMGS * IMGS * NCHAN);
        unsigned int u0 = fv32[((size_t)ry0 * IMGS + bx) * 32 + lane];
        unsigned int u1 = fv32[((size_t)ry1 * IMGS + bx) * 32 + lane];

        float w0 = wxk * wyr0, w1 = wxk * wyr1;
        accx += __uint_as_float(u0 << 16) * w0 + __uint_as_float(u1 << 16) * w1;
        accy += __uint_as_float(u0 & 0xFFFF0000u) * w0
              + __uint_as_float(u1 & 0xFFFF0000u) * w1;
    }

    // combine the two column halves (lane p and lane p+32 hold same channels)
    accx += __shfl_xor(accx, 32, 64);
    accy += __shfl_xor(accy, 32, 64);

    float r = 1.f / wsum;
    if (lhalf == 0) {
        f32x2 o; o.x = accx * r; o.y = accy * r;
        __builtin_nontemporal_store(o,
            reinterpret_cast<f32x2*>(out + (size_t)n * NCHAN) + cp);
    }
}

// ---------------------------------------------------------------------------
// Fallback (small ws): direct f32 gather from [V,C,S,S], unsorted.
// ---------------------------------------------------------------------------
__global__ __launch_bounds__(256) void project_sample_direct_kernel(
    const float* __restrict__ verts,
    const int* __restrict__ faces,
    const float* __restrict__ cam_rot,
    const float* __restrict__ cam_trans,
    const float* __restrict__ Kmat,
    const float* __restrict__ feature,
    const unsigned char* __restrict__ table,
    float* __restrict__ out,
    int n_verts)
{
    int n = blockIdx.x * 4 + (threadIdx.x >> 6);
    int c = threadIdx.x & 63;
    if (n >= n_verts) return;

    float px = verts[n * 3 + 0], py = verts[n * 3 + 1], pz = verts[n * 3 + 2];
    int f = faces[n];
    float xs[NVIEW], ys[NVIEW], mask[NVIEW];
    float vsum = 0.f;
#pragma unroll
    for (int v = 0; v < NVIEW; ++v) {
        project_view(cam_rot, cam_trans, Kmat, v, px, py, pz, xs[v], ys[v]);
        float m = (f >= 0 && table[(size_t)v * NUM_FACES + f]) ? 1.f : 0.f;
        mask[v] = m; vsum += m;
    }
    float wsum = vsum;
    if (vsum == 0.f) {
#pragma unroll
        for (int v = 0; v < NVIEW; ++v) mask[v] = 1.f;
        wsum = (float)NVIEW;
    }
    float acc = 0.f;
#pragma unroll
    for (int v = 0; v < NVIEW; ++v) {
        if (mask[v] == 0.f) continue;
        float x = xs[v], y = ys[v];
        float x0f = floorf(x), y0f = floorf(y);
        float wx1 = x - x0f, wx0 = 1.f - wx1;
        float wy1 = y - y0f, wy0 = 1.f - wy1;
        int x0 = (int)x0f, y0 = (int)y0f;
        int x1 = x0 + 1, y1 = y0 + 1;
        bool vx0 = (x0 >= 0) && (x0 <= IMGS - 1), vx1 = (x1 >= 0) && (x1 <= IMGS - 1);
        bool vy0 = (y0 >= 0) && (y0 <= IMGS - 1), vy1 = (y1 >= 0) && (y1 <= IMGS - 1);
        int cx0 = min(max(x0, 0), IMGS - 1), cx1 = min(max(x1, 0), IMGS - 1);
        int cy0 = min(max(y0, 0), IMGS - 1), cy1 = min(max(y1, 0), IMGS - 1);
        const float* fc = feature + ((size_t)v * NCHAN + c) * (size_t)(IMGS * IMGS);
        acc += fc[cy0 * IMGS + cx0] * (wx0 * wy0 * (float)(vx0 && vy0))
             + fc[cy0 * IMGS + cx1] * (wx1 * wy0 * (float)(vx1 && vy0))
             + fc[cy1 * IMGS + cx0] * (wx0 * wy1 * (float)(vx0 && vy1))
             + fc[cy1 * IMGS + cx1] * (wx1 * wy1 * (float)(vx1 && vy1));
    }
    out[(size_t)n * NCHAN + c] = acc / wsum;
}

extern "C" void kernel_launch(void* const* d_in, const int* in_sizes, int n_in,
                              void* d_out, int out_size, void* d_ws, size_t ws_size,
                              hipStream_t stream) {
    const float* verts     = (const float*)d_in[0];
    const int*   faces     = (const int*)d_in[1];
    const float* cam_rot   = (const float*)d_in[2];
    const float* cam_trans = (const float*)d_in[3];
    const float* Kmat      = (const float*)d_in[4];
    const float* feature   = (const float*)d_in[6];
    const int*   p2f       = (const int*)d_in[7];
    float* out = (float*)d_out;

    int n_verts = in_sizes[1];

    // d_ws layout: [table][flags][hist][offs][tileid][perm][align][feat_t]
    size_t table_off  = 0;
    size_t table_sz   = (size_t)NVIEW * NUM_FACES;
    size_t flag_off   = table_off + table_sz;
    size_t flag_sz    = (size_t)NVIEW * IMGS * XTILES;
    size_t hist_off   = flag_off + flag_sz;
    size_t hist_sz    = NBUCKET * sizeof(int);
    size_t offs_off   = hist_off + hist_sz;
    size_t offs_sz    = NBUCKET * sizeof(int);
    size_t tile_off   = offs_off + offs_sz;
    size_t tile_sz    = (size_t)n_verts * sizeof(int);
    size_t perm_off   = tile_off + tile_sz;
    size_t perm_sz    = (size_t)n_verts * sizeof(int);
    size_t feat_off   = (perm_off + perm_sz + 255) & ~(size_t)255;
    size_t feat_sz    = (size_t)NVIEW * IMGS * IMGS * NCHAN * sizeof(unsigned short);
    bool use_fast = (ws_size >= feat_off + feat_sz);

    unsigned char* table = (unsigned char*)d_ws + table_off;
    unsigned char* flags = (unsigned char*)d_ws + flag_off;
    int* hist   = (int*)((char*)d_ws + hist_off);
    int* offs   = (int*)((char*)d_ws + offs_off);
    int* tileid = (int*)((char*)d_ws + tile_off);
    int* perm   = (int*)((char*)d_ws + perm_off);

    const int total_pix = NVIEW * IMGS * IMGS;  // multiple of 256
    int nblocks = (n_verts + 3) / 4;

    if (use_fast) {
        unsigned short* feat_t = (unsigned short*)((char*)d_ws + feat_off);
        // zero table + flags + hist in one memset (contiguous)
        hipMemsetAsync((char*)d_ws, 0, hist_off + hist_sz, stream);

        int prep_total = total_pix + n_verts * NVIEW;
        prep_kernel<<<(prep_total + 255) / 256, 256, 0, stream>>>(
            p2f, table, verts, cam_rot, cam_trans, Kmat, flags, hist, tileid, n_verts);
        scan_kernel<<<1, NBUCKET, 0, stream>>>(hist, offs);
        scatter_perm_kernel<<<(n_verts + 255) / 256, 256, 0, stream>>>(
            tileid, offs, perm, n_verts);
        transpose_feat_kernel<<<NVIEW * IMGS * XTILES, 256, 0, stream>>>(
            feature, feat_t, flags);
        int sgrid = (nblocks + 7) & ~7;  // pad to multiple of 8 for XCD swizzle
        project_sample_sorted_kernel<<<sgrid, 256, 0, stream>>>(
            verts, faces, cam_rot, cam_trans, Kmat, feat_t, table, perm, out, n_verts);
    } else {
        hipMemsetAsync(table, 0, table_sz, stream);
        prep_kernel<<<(total_pix + 255) / 256, 256, 0, stream>>>(
            p2f, table, verts, cam_rot, cam_trans, Kmat, flags, hist, tileid, 0);
        project_sample_direct_kernel<<<nblocks, 256, 0, stream>>>(
            verts, faces, cam_rot, cam_trans, Kmat, feature, table, out, n_verts);
    }
}

// Round 8
// 187.715 us; speedup vs baseline: 2.1644x; 2.1644x over previous
//
#include <hip/hip_runtime.h>

#define NUM_FACES 400000
#define NVIEW 4
#define NCHAN 64
#define IMGS 512
#define XTILES (IMGS / 64)

typedef float f32x4 __attribute__((ext_vector_type(4)));

__device__ __forceinline__ float bf2f(unsigned short u) {
    union { unsigned int i; float f; } x; x.i = ((unsigned int)u) << 16; return x.f;
}
__device__ __forceinline__ unsigned short f2bf(float f) {
    unsigned int u = __float_as_uint(f);
    return (unsigned short)((u + 0x7FFFu + ((u >> 16) & 1u)) >> 16);  // RNE
}

__device__ __forceinline__ void project_view(
    const float* __restrict__ cam_rot, const float* __restrict__ cam_trans,
    const float* __restrict__ Kmat, int v, float px, float py, float pz,
    float& x, float& y)
{
    const float* R  = cam_rot   + v * 9;
    const float* t  = cam_trans + v * 3;
    const float* Km = Kmat      + v * 9;
    float cx = R[0] * px + R[1] * py + R[2] * pz + t[0];
    float cy = R[3] * px + R[4] * py + R[5] * pz + t[1];
    float cz = R[6] * px + R[7] * py + R[8] * pz + t[2];
    float qx = Km[0] * cx + Km[1] * cy + Km[2] * cz;
    float qy = Km[3] * cx + Km[4] * cy + Km[5] * cz;
    float qz = Km[6] * cx + Km[7] * cy + Km[8] * cz;
    x = qx / qz;
    y = qy / qz;
}

// ---------------------------------------------------------------------------
// Kernel -1: zero the [table][flags] region. Replaces hipMemsetAsync, whose
// rocclr fill kernel ran at 10 GB/s (~155 us for 1.6 MB — the hidden
// dominant dispatch of rounds 4-7).
// ---------------------------------------------------------------------------
__global__ void zero_ws_kernel(uint4* __restrict__ p, int n16) {
    int i = blockIdx.x * blockDim.x + threadIdx.x;
    if (i < n16) p[i] = make_uint4(0u, 0u, 0u, 0u);
}

// ---------------------------------------------------------------------------
// Kernel 0 (fused): [0,total_pix) scatters pix_to_face into the visibility
// table; [total_pix, total_pix+N*V) projects vertex x view and marks touched
// (v,y,x-tile) flags. Block-aligned range split. Racy same-value byte
// stores are fine. NO atomics (R7 lesson: hot-bucket atomic serialization).
// ---------------------------------------------------------------------------
__global__ void prep_kernel(const int* __restrict__ p2f,
                            unsigned char* __restrict__ table,   // [V,NUM_FACES]
                            const float* __restrict__ verts,
                            const float* __restrict__ cam_rot,
                            const float* __restrict__ cam_trans,
                            const float* __restrict__ Kmat,
                            unsigned char* __restrict__ flags,   // [V,S,XTILES]
                            int n_verts) {
    const int total_pix = NVIEW * IMGS * IMGS;
    int i = blockIdx.x * blockDim.x + threadIdx.x;
    if (i < total_pix) {
        int v = i / (IMGS * IMGS);
        int f = p2f[i];
        if (f >= 0) table[(size_t)v * NUM_FACES + f] = 1;
        return;
    }
    int j = i - total_pix;
    int n = j >> 2;
    int v = j & 3;
    if (n >= n_verts) return;
    float px = verts[n * 3 + 0], py = verts[n * 3 + 1], pz = verts[n * 3 + 2];
    float x, y;
    project_view(cam_rot, cam_trans, Kmat, v, px, py, pz, x, y);
    int x0 = (int)floorf(x), y0 = (int)floorf(y);
    int cx0 = min(max(x0, 0), IMGS - 1);
    int cx1 = min(max(x0 + 1, 0), IMGS - 1);
    int cy0 = min(max(y0, 0), IMGS - 1);
    int cy1 = min(max(y0 + 1, 0), IMGS - 1);
    unsigned char* fv = flags + (size_t)v * IMGS * XTILES;
    int t00 = cy0 * XTILES + (cx0 >> 6);
    int t10 = cy0 * XTILES + (cx1 >> 6);
    int t01 = cy1 * XTILES + (cx0 >> 6);
    int t11 = cy1 * XTILES + (cx1 >> 6);
    fv[t00] = 1;
    if (t10 != t00) fv[t10] = 1;
    fv[t01] = 1;
    if (t11 != t01) fv[t11] = 1;
}

// ---------------------------------------------------------------------------
// Kernel 1: transpose feature [V,C,S,S] f32 -> [V,S,S,C] bf16, skipping
// untouched tiles. f32 reads nontemporal (read-once stream, don't evict
// feat_t from LLC). LDS stride 65: <=2-way bank aliasing (free).
// ---------------------------------------------------------------------------
__global__ __launch_bounds__(256) void transpose_feat_kernel(
    const float* __restrict__ feature,
    unsigned short* __restrict__ feat_t,
    const unsigned char* __restrict__ flags)
{
    int b = blockIdx.x;
    int xt = b % XTILES;
    int y  = (b / XTILES) % IMGS;
    int v  = b / (XTILES * IMGS);
    if (!flags[((size_t)v * IMGS + y) * XTILES + xt]) return;

    __shared__ float tile[64 * 65];
    int x0 = xt * 64;
    const size_t SS = (size_t)IMGS * IMGS;

    const float* src = feature + (size_t)v * NCHAN * SS + (size_t)y * IMGS + x0;
#pragma unroll
    for (int i = 0; i < 4; ++i) {
        int lin = i * 256 + threadIdx.x;
        int c  = lin >> 4;
        int xq = (lin & 15) * 4;
        f32x4 val = __builtin_nontemporal_load(
            reinterpret_cast<const f32x4*>(src + (size_t)c * SS + xq));
        tile[c * 65 + xq + 0] = val.x;
        tile[c * 65 + xq + 1] = val.y;
        tile[c * 65 + xq + 2] = val.z;
        tile[c * 65 + xq + 3] = val.w;
    }
    __syncthreads();

    unsigned short* dst = feat_t + (((size_t)v * IMGS + y) * IMGS + x0) * NCHAN;
#pragma unroll
    for (int i = 0; i < 4; ++i) {
        int lin = i * 256 + threadIdx.x;
        int x  = lin >> 4;
        int c0 = (lin & 15) * 4;
        ushort4 w;
        w.x = f2bf(tile[(c0 + 0) * 65 + x]);
        w.y = f2bf(tile[(c0 + 1) * 65 + x]);
        w.z = f2bf(tile[(c0 + 2) * 65 + x]);
        w.w = f2bf(tile[(c0 + 3) * 65 + x]);
        *reinterpret_cast<ushort4*>(dst + (size_t)x * NCHAN + c0) = w;
    }
}

// ---------------------------------------------------------------------------
// Kernel 2: project + mask + bilinear sample (bf16 feat_t) + weighted mean.
// Block = 256 = 4 vertices x 64 channels; one wave per vertex so the
// per-view skip is wave-uniform. out store nontemporal (write-once).
// ---------------------------------------------------------------------------
__global__ __launch_bounds__(256) void project_sample_bf16_kernel(
    const float* __restrict__ verts,
    const int* __restrict__ faces,
    const float* __restrict__ cam_rot,
    const float* __restrict__ cam_trans,
    const float* __restrict__ Kmat,
    const unsigned short* __restrict__ feat_t,   // [V,S,S,C] bf16
    const unsigned char* __restrict__ table,     // [V,NUM_FACES]
    float* __restrict__ out,                     // [N,C]
    int n_verts)
{
    int n = blockIdx.x * 4 + (threadIdx.x >> 6);
    int c = threadIdx.x & 63;
    if (n >= n_verts) return;

    float px = verts[n * 3 + 0];
    float py = verts[n * 3 + 1];
    float pz = verts[n * 3 + 2];
    int f = faces[n];

    float xs[NVIEW], ys[NVIEW], mask[NVIEW];
    float vsum = 0.f;

#pragma unroll
    for (int v = 0; v < NVIEW; ++v) {
        project_view(cam_rot, cam_trans, Kmat, v, px, py, pz, xs[v], ys[v]);
        float m = (f >= 0 && table[(size_t)v * NUM_FACES + f]) ? 1.f : 0.f;
        mask[v] = m;
        vsum += m;
    }

    float wsum = vsum;
    if (vsum == 0.f) {
#pragma unroll
        for (int v = 0; v < NVIEW; ++v) mask[v] = 1.f;
        wsum = (float)NVIEW;
    }

    float acc = 0.f;
#pragma unroll
    for (int v = 0; v < NVIEW; ++v) {
        if (mask[v] == 0.f) continue;  // wave-uniform skip
        float x = xs[v], y = ys[v];
        float x0f = floorf(x), y0f = floorf(y);
        float wx1 = x - x0f, wx0 = 1.f - wx1;
        float wy1 = y - y0f, wy0 = 1.f - wy1;
        int x0 = (int)x0f, y0 = (int)y0f;
        int x1 = x0 + 1, y1 = y0 + 1;
        bool vx0 = (x0 >= 0) && (x0 <= IMGS - 1);
        bool vx1 = (x1 >= 0) && (x1 <= IMGS - 1);
        bool vy0 = (y0 >= 0) && (y0 <= IMGS - 1);
        bool vy1 = (y1 >= 0) && (y1 <= IMGS - 1);
        int cx0 = min(max(x0, 0), IMGS - 1);
        int cx1 = min(max(x1, 0), IMGS - 1);
        int cy0 = min(max(y0, 0), IMGS - 1);
        int cy1 = min(max(y1, 0), IMGS - 1);

        float w00 = wx0 * wy0 * (float)(vx0 && vy0);
        float w10 = wx1 * wy0 * (float)(vx1 && vy0);
        float w01 = wx0 * wy1 * (float)(vx0 && vy1);
        float w11 = wx1 * wy1 * (float)(vx1 && vy1);

        const unsigned short* fv = feat_t + (size_t)v * IMGS * IMGS * NCHAN;
        const unsigned short* p00 = fv + ((size_t)cy0 * IMGS + cx0) * NCHAN;
        const unsigned short* p10 = fv + ((size_t)cy0 * IMGS + cx1) * NCHAN;
        const unsigned short* p01 = fv + ((size_t)cy1 * IMGS + cx0) * NCHAN;
        const unsigned short* p11 = fv + ((size_t)cy1 * IMGS + cx1) * NCHAN;
        acc += bf2f(p00[c]) * w00 + bf2f(p10[c]) * w10
             + bf2f(p01[c]) * w01 + bf2f(p11[c]) * w11;
    }

    __builtin_nontemporal_store(acc / wsum, out + (size_t)n * NCHAN + c);
}

// ---------------------------------------------------------------------------
// Fallback (small ws): direct f32 gather from [V,C,S,S].
// ---------------------------------------------------------------------------
__global__ __launch_bounds__(256) void project_sample_direct_kernel(
    const float* __restrict__ verts,
    const int* __restrict__ faces,
    const float* __restrict__ cam_rot,
    const float* __restrict__ cam_trans,
    const float* __restrict__ Kmat,
    const float* __restrict__ feature,
    const unsigned char* __restrict__ table,
    float* __restrict__ out,
    int n_verts)
{
    int n = blockIdx.x * 4 + (threadIdx.x >> 6);
    int c = threadIdx.x & 63;
    if (n >= n_verts) return;

    float px = verts[n * 3 + 0], py = verts[n * 3 + 1], pz = verts[n * 3 + 2];
    int f = faces[n];
    float xs[NVIEW], ys[NVIEW], mask[NVIEW];
    float vsum = 0.f;
#pragma unroll
    for (int v = 0; v < NVIEW; ++v) {
        project_view(cam_rot, cam_trans, Kmat, v, px, py, pz, xs[v], ys[v]);
        float m = (f >= 0 && table[(size_t)v * NUM_FACES + f]) ? 1.f : 0.f;
        mask[v] = m; vsum += m;
    }
    float wsum = vsum;
    if (vsum == 0.f) {
#pragma unroll
        for (int v = 0; v < NVIEW; ++v) mask[v] = 1.f;
        wsum = (float)NVIEW;
    }
    float acc = 0.f;
#pragma unroll
    for (int v = 0; v < NVIEW; ++v) {
        if (mask[v] == 0.f) continue;
        float x = xs[v], y = ys[v];
        float x0f = floorf(x), y0f = floorf(y);
        float wx1 = x - x0f, wx0 = 1.f - wx1;
        float wy1 = y - y0f, wy0 = 1.f - wy1;
        int x0 = (int)x0f, y0 = (int)y0f;
        int x1 = x0 + 1, y1 = y0 + 1;
        bool vx0 = (x0 >= 0) && (x0 <= IMGS - 1), vx1 = (x1 >= 0) && (x1 <= IMGS - 1);
        bool vy0 = (y0 >= 0) && (y0 <= IMGS - 1), vy1 = (y1 >= 0) && (y1 <= IMGS - 1);
        int cx0 = min(max(x0, 0), IMGS - 1), cx1 = min(max(x1, 0), IMGS - 1);
        int cy0 = min(max(y0, 0), IMGS - 1), cy1 = min(max(y1, 0), IMGS - 1);
        const float* fc = feature + ((size_t)v * NCHAN + c) * (size_t)(IMGS * IMGS);
        acc += fc[cy0 * IMGS + cx0] * (wx0 * wy0 * (float)(vx0 && vy0))
             + fc[cy0 * IMGS + cx1] * (wx1 * wy0 * (float)(vx1 && vy0))
             + fc[cy1 * IMGS + cx0] * (wx0 * wy1 * (float)(vx0 && vy1))
             + fc[cy1 * IMGS + cx1] * (wx1 * wy1 * (float)(vx1 && vy1));
    }
    out[(size_t)n * NCHAN + c] = acc / wsum;
}

extern "C" void kernel_launch(void* const* d_in, const int* in_sizes, int n_in,
                              void* d_out, int out_size, void* d_ws, size_t ws_size,
                              hipStream_t stream) {
    const float* verts     = (const float*)d_in[0];
    const int*   faces     = (const int*)d_in[1];
    const float* cam_rot   = (const float*)d_in[2];
    const float* cam_trans = (const float*)d_in[3];
    const float* Kmat      = (const float*)d_in[4];
    const float* feature   = (const float*)d_in[6];
    const int*   p2f       = (const int*)d_in[7];
    float* out = (float*)d_out;

    int n_verts = in_sizes[1];

    // d_ws layout: [vis table][tile flags][align][feat_t bf16]
    unsigned char* table = (unsigned char*)d_ws;
    size_t table_bytes = (size_t)NVIEW * NUM_FACES;
    size_t flag_off   = table_bytes;
    size_t flag_bytes = (size_t)NVIEW * IMGS * XTILES;
    size_t feat_off   = (flag_off + flag_bytes + 255) & ~(size_t)255;
    size_t feat_bytes = (size_t)NVIEW * IMGS * IMGS * NCHAN * sizeof(unsigned short);
    bool use_transpose = (ws_size >= feat_off + feat_bytes);

    // custom zero of table+flags (1.62 MB, multiple of 16 B)
    size_t zero_bytes = flag_off + flag_bytes;
    int n16 = (int)(zero_bytes / 16);   // 1616384/16 = 101024 exactly
    zero_ws_kernel<<<(n16 + 255) / 256, 256, 0, stream>>>((uint4*)d_ws, n16);

    const int total_pix = NVIEW * IMGS * IMGS;  // multiple of 256
    int nblocks = (n_verts + 3) / 4;
    if (use_transpose) {
        unsigned char* flags = (unsigned char*)d_ws + flag_off;
        unsigned short* feat_t = (unsigned short*)((char*)d_ws + feat_off);
        int prep_total = total_pix + n_verts * NVIEW;
        prep_kernel<<<(prep_total + 255) / 256, 256, 0, stream>>>(
            p2f, table, verts, cam_rot, cam_trans, Kmat, flags, n_verts);
        transpose_feat_kernel<<<NVIEW * IMGS * XTILES, 256, 0, stream>>>(
            feature, feat_t, flags);
        project_sample_bf16_kernel<<<nblocks, 256, 0, stream>>>(
            verts, faces, cam_rot, cam_trans, Kmat, feat_t, table, out, n_verts);
    } else {
        prep_kernel<<<(total_pix + 255) / 256, 256, 0, stream>>>(
            p2f, table, verts, cam_rot, cam_trans, Kmat,
            (unsigned char*)d_ws + flag_off, n_verts);
        project_sample_direct_kernel<<<nblocks, 256, 0, stream>>>(
            verts, faces, cam_rot, cam_trans, Kmat, feature, table, out, n_verts);
    }
}